// Round 2
// baseline (201.098 us; speedup 1.0000x reference)
//
#include <hip/hip_runtime.h>
#include <hip/hip_bf16.h>

#define N_PTS 16384
#define PER   2048
#define M_CTR 4096
#define KNB   64
#define C_IN  128
#define HID   256
#define C_OUT 256

typedef unsigned short u16;
typedef __attribute__((ext_vector_type(8))) short s8v;    // 8 bf16 (4 VGPRs)
typedef __attribute__((ext_vector_type(4))) float f4v;
typedef __attribute__((ext_vector_type(4))) unsigned int u4v;

static __device__ __forceinline__ float bf2f(u16 u) {
    union { unsigned int i; float f; } v; v.i = ((unsigned int)u) << 16; return v.f;
}
static __device__ __forceinline__ u16 f2bf(float f) {
    union { float f; unsigned int i; } v; v.f = f;
    unsigned int r = v.i + 0x7FFFu + ((v.i >> 16) & 1u);
    return (u16)(r >> 16);
}

// ---------------------------------------------------------------- prep: transpose weights to bf16
__global__ __launch_bounds__(256) void prep_kernel(
        const float* __restrict__ W1, const float* __restrict__ W2,
        u16* __restrict__ W1aT, u16* __restrict__ W1bT, u16* __restrict__ W2T) {
    int gid = blockIdx.x * 256 + threadIdx.x;            // 65536 threads
    int c = gid >> 8, k = gid & 255;
    W2T[gid] = f2bf(W2[k * 256 + c]);                    // W2T[c][k] = W2[k][c]
    if (gid < 32768) {
        int c1 = gid >> 7, k1 = gid & 127;
        W1aT[gid] = f2bf(W1[k1 * 256 + c1]);             // rows 0:128   (x_nbr part)
        W1bT[gid] = f2bf(W1[(k1 + 128) * 256 + c1]);     // rows 128:256 (x_dst part)
    }
}

// ---------------------------------------------------------------- ball query
// Replicates the reference's float32 gemm-trick d2 EXACTLY:
//   A = ((cx*cx + cy*cy) + cz*cz)        sequential fp32, no fma (numpy **2 + sum)
//   B likewise per point
//   C = (2c)x*px fma-chained             ((2.0*pos_c) @ pos.T -> BLAS sgemm, K=3)
//   d2 = (A + B) - C                     fp32
// so near-boundary / rank-64 tie decisions match the numpy reference.
__global__ __launch_bounds__(256) void ballq_kernel(
        const float* __restrict__ pos, int* __restrict__ nbr, int* __restrict__ cnt) {
    __shared__ float cd2[1024];
    __shared__ int   cidx[1024];
    __shared__ int   s_n;
    int m = blockIdx.x, tid = threadIdx.x;
    int c = m * 4;
    int base = (m >> 9) << 11;                            // cloud start
    if (tid == 0) s_n = 0;
    __syncthreads();
    float cx = pos[c * 3 + 0], cy = pos[c * 3 + 1], cz = pos[c * 3 + 2];
    float A = __fadd_rn(__fadd_rn(__fmul_rn(cx, cx), __fmul_rn(cy, cy)), __fmul_rn(cz, cz));
    float c2x = __fmul_rn(2.0f, cx);
    float c2y = __fmul_rn(2.0f, cy);
    float c2z = __fmul_rn(2.0f, cz);
    for (int s = 0; s < 8; ++s) {
        int j = base + tid + (s << 8);
        float px = pos[j * 3 + 0], py = pos[j * 3 + 1], pz = pos[j * 3 + 2];
        float B = __fadd_rn(__fadd_rn(__fmul_rn(px, px), __fmul_rn(py, py)), __fmul_rn(pz, pz));
        float C = __fmaf_rn(c2z, pz, __fmaf_rn(c2y, py, __fmul_rn(c2x, px)));
        float d2 = __fsub_rn(__fadd_rn(A, B), C);
        if (d2 <= 0.0625f) {
            int a = atomicAdd(&s_n, 1);
            if (a < 1024) { cd2[a] = d2; cidx[a] = j; }
        }
    }
    __syncthreads();
    int V = s_n < 1024 ? s_n : 1024;
    if (V <= KNB) {
        if (tid < KNB) nbr[m * KNB + tid] = (tid < V) ? cidx[tid] : c;
        if (tid == 0) cnt[m] = V;
    } else {
        for (int e = tid; e < V; e += 256) {
            float de = cd2[e]; int ie = cidx[e];
            int rank = 0;
            for (int q = 0; q < V; ++q) {
                float dq = cd2[q];
                rank += (dq < de) || (dq == de && cidx[q] < ie);
            }
            if (rank < KNB) nbr[m * KNB + rank] = cidx[e];
        }
        if (tid == 0) cnt[m] = KNB;
    }
}

// ---------------------------------------------------------------- u = x@W1a (MODE 0, bf16 out) / v = x[4m]@W1b + b1 (MODE 1, f32 out)
template <int MODE>
__global__ __launch_bounds__(256) void gemm_xw_kernel(
        const float* __restrict__ x, const u16* __restrict__ WT,
        const float* __restrict__ b1, u16* __restrict__ u_out, float* __restrict__ v_out) {
    __shared__ u16 x_lds[64 * 136];                       // 64 rows x 128 k, pad to 136
    int tid = threadIdx.x, blk = blockIdx.x;
    // stage x rows (fp32 -> bf16)
    {
        int r = tid >> 2, q = tid & 3;
        int xrow = blk * 64 + r;
        if (MODE == 1) xrow *= 4;
        const float* xp = x + xrow * C_IN + q * 32;
        u16* dst = x_lds + r * 136 + q * 32;
        for (int i = 0; i < 8; ++i) {
            f4v f = *(const f4v*)(xp + i * 4);
            dst[i * 4 + 0] = f2bf(f[0]);
            dst[i * 4 + 1] = f2bf(f[1]);
            dst[i * 4 + 2] = f2bf(f[2]);
            dst[i * 4 + 3] = f2bf(f[3]);
        }
    }
    __syncthreads();
    int lane = tid & 63, w = tid >> 6;
    int quad = lane >> 4, l16 = lane & 15;
    int cb = w * 64;
    f4v acc[4][4] = {};
    for (int k0 = 0; k0 < 128; k0 += 32) {
        s8v a[4], b[4];
        for (int rt = 0; rt < 4; ++rt)
            a[rt] = *(const s8v*)&x_lds[(rt * 16 + l16) * 136 + k0 + quad * 8];
        for (int ct = 0; ct < 4; ++ct)
            b[ct] = *(const s8v*)(WT + (cb + ct * 16 + l16) * 128 + k0 + quad * 8);
        for (int rt = 0; rt < 4; ++rt)
            for (int ct = 0; ct < 4; ++ct)
                acc[rt][ct] = __builtin_amdgcn_mfma_f32_16x16x32_bf16(a[rt], b[ct], acc[rt][ct], 0, 0, 0);
    }
    for (int rt = 0; rt < 4; ++rt)
        for (int ct = 0; ct < 4; ++ct)
            for (int g = 0; g < 4; ++g) {
                int row = rt * 16 + quad * 4 + g;
                int col = cb + ct * 16 + l16;
                float val = acc[rt][ct][g];
                int orow = blk * 64 + row;
                if (MODE == 0) u_out[orow * 256 + col] = f2bf(val);
                else           v_out[orow * 256 + col] = val + b1[col];
            }
}

// ---------------------------------------------------------------- fused edge conv: h assembly + GEMM2 + masked max
__global__ __launch_bounds__(256) void edge_kernel(
        const u16* __restrict__ u, const float* __restrict__ v,
        const u16* __restrict__ W2T, const float* __restrict__ W1,
        const float* __restrict__ b2, const float* __restrict__ pos,
        const float* __restrict__ lframes, const int* __restrict__ batch,
        const int* __restrict__ nbr, const int* __restrict__ cnt,
        float* __restrict__ out0, float* __restrict__ out_pos,
        float* __restrict__ out_batch, float* __restrict__ out_lf) {
    __shared__ u16   h_lds[64 * 264];                     // 64 x 256 bf16, pad to 264
    __shared__ float relc_lds[64 * 4];
    __shared__ float v_lds[256];
    __shared__ float w1c_lds[768];
    __shared__ int   nbr_lds[64];
    __shared__ int   s_cnt;

    int m = blockIdx.x, tid = threadIdx.x;
    int c = m * 4;
    v_lds[tid] = v[m * 256 + tid];
    for (int i = tid; i < 768; i += 256) w1c_lds[i] = W1[65536 + i];   // W1 rows 256..258
    if (tid == 0) s_cnt = cnt[m];
    if (tid < 64) {
        int j = nbr[m * KNB + tid];
        nbr_lds[tid] = j;
        float rx = pos[j * 3 + 0] - pos[c * 3 + 0];
        float ry = pos[j * 3 + 1] - pos[c * 3 + 1];
        float rz = pos[j * 3 + 2] - pos[c * 3 + 2];
        const float* lf = lframes + c * 9;
        relc_lds[tid * 4 + 0] = lf[0] * rx + lf[1] * ry + lf[2] * rz;
        relc_lds[tid * 4 + 1] = lf[3] * rx + lf[4] * ry + lf[5] * rz;
        relc_lds[tid * 4 + 2] = lf[6] * rx + lf[7] * ry + lf[8] * rz;
    }
    if (tid < 3)  out_pos[m * 3 + tid] = pos[c * 3 + tid];
    if (tid == 3) out_batch[m] = (float)batch[c];
    if (tid >= 4 && tid < 13) out_lf[m * 9 + (tid - 4)] = lframes[c * 9 + (tid - 4)];
    __syncthreads();

    // phase 1: h = relu(u[nbr] + v + relc @ W1c) -> bf16 LDS
    {
        int k = tid >> 2, q = tid & 3;
        int j = nbr_lds[k];
        float r0 = relc_lds[k * 4 + 0], r1 = relc_lds[k * 4 + 1], r2 = relc_lds[k * 4 + 2];
        const u16* urow = u + j * 256 + q * 64;
        u16* hrow = h_lds + k * 264 + q * 64;
        for (int i = 0; i < 8; ++i) {
            union { u4v v4; u16 us[8]; } uu;
            uu.v4 = *(const u4v*)(urow + i * 8);
            union { u4v v4; u16 us[8]; } hh;
            for (int e = 0; e < 8; ++e) {
                int col = q * 64 + i * 8 + e;
                float pre = v_lds[col] + bf2f(uu.us[e])
                          + r0 * w1c_lds[col] + r1 * w1c_lds[256 + col] + r2 * w1c_lds[512 + col];
                hh.us[e] = f2bf(fmaxf(pre, 0.0f));
            }
            *(u4v*)(hrow + i * 8) = hh.v4;
        }
    }
    __syncthreads();

    // phase 2: [64x256] @ [256x256] ; wave w -> cols [64w, 64w+64)
    int lane = tid & 63, w = tid >> 6;
    int quad = lane >> 4, l16 = lane & 15;
    int cb = w * 64;
    f4v acc[4][4] = {};
    for (int k0 = 0; k0 < 256; k0 += 32) {
        s8v a[4], b[4];
        for (int rt = 0; rt < 4; ++rt)
            a[rt] = *(const s8v*)&h_lds[(rt * 16 + l16) * 264 + k0 + quad * 8];
        for (int ct = 0; ct < 4; ++ct)
            b[ct] = *(const s8v*)(W2T + (cb + ct * 16 + l16) * 256 + k0 + quad * 8);
        for (int rt = 0; rt < 4; ++rt)
            for (int ct = 0; ct < 4; ++ct)
                acc[rt][ct] = __builtin_amdgcn_mfma_f32_16x16x32_bf16(a[rt], b[ct], acc[rt][ct], 0, 0, 0);
    }
    // masked max over neighbor rows, then + b2
    int cv = s_cnt;
    for (int ct = 0; ct < 4; ++ct) {
        float mx = -__builtin_inff();
        for (int rt = 0; rt < 4; ++rt)
            for (int g = 0; g < 4; ++g) {
                int row = rt * 16 + quad * 4 + g;
                float val = acc[rt][ct][g];
                if (row < cv) mx = fmaxf(mx, val);
            }
        mx = fmaxf(mx, __shfl_xor(mx, 16, 64));
        mx = fmaxf(mx, __shfl_xor(mx, 32, 64));
        if (lane < 16) {
            int col = cb + ct * 16 + l16;
            out0[m * 256 + col] = mx + b2[col];
        }
    }
}

extern "C" void kernel_launch(void* const* d_in, const int* in_sizes, int n_in,
                              void* d_out, int out_size, void* d_ws, size_t ws_size,
                              hipStream_t stream) {
    const float* x       = (const float*)d_in[0];
    const float* pos     = (const float*)d_in[1];
    const int*   batch   = (const int*)d_in[2];
    const float* lframes = (const float*)d_in[3];
    const float* W1      = (const float*)d_in[4];
    const float* b1      = (const float*)d_in[5];
    const float* W2      = (const float*)d_in[6];
    const float* b2      = (const float*)d_in[7];

    float* out       = (float*)d_out;
    float* out_pos   = out + M_CTR * 256;        // 1048576
    float* out_batch = out_pos + M_CTR * 3;      // +12288
    float* out_lf    = out_batch + M_CTR;        // +4096

    char* ws = (char*)d_ws;
    u16*   u_ws = (u16*)(ws);                    // N*256 bf16   = 8 MB
    float* v_ws = (float*)(ws + 8388608);        // M*256 f32    = 4 MB
    u16*   W1aT = (u16*)(ws + 12582912);         // 256*128 bf16
    u16*   W1bT = (u16*)(ws + 12648448);         // 256*128 bf16
    u16*   W2T  = (u16*)(ws + 12713984);         // 256*256 bf16
    int*   nbr  = (int*)(ws + 12845056);         // M*64 int
    int*   cntp = (int*)(ws + 13893632);         // M int

    hipLaunchKernelGGL(prep_kernel, dim3(256), dim3(256), 0, stream, W1, W2, W1aT, W1bT, W2T);
    hipLaunchKernelGGL(ballq_kernel, dim3(M_CTR), dim3(256), 0, stream, pos, nbr, cntp);
    hipLaunchKernelGGL((gemm_xw_kernel<0>), dim3(N_PTS / 64), dim3(256), 0, stream,
                       x, W1aT, b1, u_ws, v_ws);
    hipLaunchKernelGGL((gemm_xw_kernel<1>), dim3(M_CTR / 64), dim3(256), 0, stream,
                       x, W1bT, b1, u_ws, v_ws);
    hipLaunchKernelGGL(edge_kernel, dim3(M_CTR), dim3(256), 0, stream,
                       u_ws, v_ws, W2T, W1, b2, pos, lframes, batch, nbr, cntp,
                       out, out_pos, out_batch, out_lf);
}

// Round 3
// 185.081 us; speedup vs baseline: 1.0865x; 1.0865x over previous
//
#include <hip/hip_runtime.h>
#include <hip/hip_bf16.h>

#define N_PTS 16384
#define PER   2048
#define M_CTR 4096
#define KNB   64
#define C_IN  128
#define HID   256
#define C_OUT 256

typedef unsigned short u16;
typedef unsigned int u32;
typedef __attribute__((ext_vector_type(8))) short s8v;    // 8 bf16 (4 VGPRs)
typedef __attribute__((ext_vector_type(4))) float f4v;
typedef __attribute__((ext_vector_type(4))) unsigned int u4v;

static __device__ __forceinline__ float bf2f(u16 u) {
    union { unsigned int i; float f; } v; v.i = ((unsigned int)u) << 16; return v.f;
}
static __device__ __forceinline__ u16 f2bf(float f) {
    union { float f; unsigned int i; } v; v.f = f;
    unsigned int r = v.i + 0x7FFFu + ((v.i >> 16) & 1u);
    return (u16)(r >> 16);
}

// ---------------------------------------------------------------- ballq (+prep folded into first 256 blocks)
// d2 replicates the reference float32 gemm-trick bit-for-bit (see r2 notes).
__global__ __launch_bounds__(256) void ballq_kernel(
        const float* __restrict__ pos, int* __restrict__ nbr, int* __restrict__ cnt,
        const float* __restrict__ W1, const float* __restrict__ W2,
        u16* __restrict__ W1aT, u16* __restrict__ W1bT, u16* __restrict__ W2T) {
    __shared__ float cd2[1024];
    __shared__ int   cidx[1024];
    __shared__ int   s_n;
    int m = blockIdx.x, tid = threadIdx.x;

    // folded prep: weight transposes to bf16 (outputs consumed next dispatch)
    if (m < 256) {
        int gid = m * 256 + tid;
        int cc = gid >> 8, k = gid & 255;
        W2T[gid] = f2bf(W2[k * 256 + cc]);               // W2T[c][k]
        if (gid < 32768) {
            int c1 = gid >> 7, k1 = gid & 127;
            W1aT[gid] = f2bf(W1[k1 * 256 + c1]);         // rows 0:128
            W1bT[gid] = f2bf(W1[(k1 + 128) * 256 + c1]); // rows 128:256
        }
    }

    int c = m * 4;
    int base = (m >> 9) << 11;                            // cloud start
    if (tid == 0) s_n = 0;
    __syncthreads();
    float cx = pos[c * 3 + 0], cy = pos[c * 3 + 1], cz = pos[c * 3 + 2];
    float A = __fadd_rn(__fadd_rn(__fmul_rn(cx, cx), __fmul_rn(cy, cy)), __fmul_rn(cz, cz));
    float c2x = __fmul_rn(2.0f, cx);
    float c2y = __fmul_rn(2.0f, cy);
    float c2z = __fmul_rn(2.0f, cz);
    for (int s = 0; s < 8; ++s) {
        int j = base + tid + (s << 8);
        float px = pos[j * 3 + 0], py = pos[j * 3 + 1], pz = pos[j * 3 + 2];
        float B = __fadd_rn(__fadd_rn(__fmul_rn(px, px), __fmul_rn(py, py)), __fmul_rn(pz, pz));
        float C = __fmaf_rn(c2z, pz, __fmaf_rn(c2y, py, __fmul_rn(c2x, px)));
        float d2 = __fsub_rn(__fadd_rn(A, B), C);
        if (d2 <= 0.0625f) {
            int a = atomicAdd(&s_n, 1);
            if (a < 1024) { cd2[a] = d2; cidx[a] = j; }
        }
    }
    __syncthreads();
    int V = s_n < 1024 ? s_n : 1024;
    if (V <= KNB) {
        if (tid < KNB) nbr[m * KNB + tid] = (tid < V) ? cidx[tid] : c;
        if (tid == 0) cnt[m] = V;
    } else {
        for (int e = tid; e < V; e += 256) {
            float de = cd2[e]; int ie = cidx[e];
            int rank = 0;
            for (int q = 0; q < V; ++q) {
                float dq = cd2[q];
                rank += (dq < de) || (dq == de && cidx[q] < ie);
            }
            if (rank < KNB) nbr[m * KNB + rank] = cidx[e];
        }
        if (tid == 0) cnt[m] = KNB;
    }
}

// ---------------------------------------------------------------- fused u = x@W1a (blocks 0..255) / v = x[4m]@W1b + b1 (blocks 256..319)
__global__ __launch_bounds__(256) void gemm_xw_kernel(
        const float* __restrict__ x, const u16* __restrict__ W1aT, const u16* __restrict__ W1bT,
        const float* __restrict__ b1, u16* __restrict__ u_out, float* __restrict__ v_out) {
    __shared__ u16 x_lds[64 * 136];                       // 64 rows x 128 k, pad 136
    int blk = blockIdx.x, tid = threadIdx.x;
    int mode = blk >= 256 ? 1 : 0;
    int bb = mode ? blk - 256 : blk;
    const u16* WT = mode ? W1bT : W1aT;
    {
        int r = tid >> 2, q = tid & 3;
        int xrow = bb * 64 + r;
        if (mode) xrow *= 4;
        const float* xp = x + xrow * C_IN + q * 32;
        u16* dst = x_lds + r * 136 + q * 32;
        for (int i = 0; i < 8; ++i) {
            f4v f = *(const f4v*)(xp + i * 4);
            dst[i * 4 + 0] = f2bf(f[0]);
            dst[i * 4 + 1] = f2bf(f[1]);
            dst[i * 4 + 2] = f2bf(f[2]);
            dst[i * 4 + 3] = f2bf(f[3]);
        }
    }
    __syncthreads();
    int lane = tid & 63, w = tid >> 6;
    int quad = lane >> 4, l16 = lane & 15;
    int cb = w * 64;
    f4v acc[4][4] = {};
    for (int k0 = 0; k0 < 128; k0 += 32) {
        s8v a[4], b[4];
        for (int rt = 0; rt < 4; ++rt)
            a[rt] = *(const s8v*)&x_lds[(rt * 16 + l16) * 136 + k0 + quad * 8];
        for (int ct = 0; ct < 4; ++ct)
            b[ct] = *(const s8v*)(WT + (cb + ct * 16 + l16) * 128 + k0 + quad * 8);
        for (int rt = 0; rt < 4; ++rt)
            for (int ct = 0; ct < 4; ++ct)
                acc[rt][ct] = __builtin_amdgcn_mfma_f32_16x16x32_bf16(a[rt], b[ct], acc[rt][ct], 0, 0, 0);
    }
    for (int rt = 0; rt < 4; ++rt)
        for (int ct = 0; ct < 4; ++ct)
            for (int g = 0; g < 4; ++g) {
                int row = rt * 16 + quad * 4 + g;
                int col = cb + ct * 16 + l16;
                float val = acc[rt][ct][g];
                int orow = bb * 64 + row;
                if (mode == 0) u_out[orow * 256 + col] = f2bf(val);
                else           v_out[orow * 256 + col] = val + b1[col];
            }
}

// ---------------------------------------------------------------- fused edge conv
__global__ __launch_bounds__(256, 4) void edge_kernel(
        const u16* __restrict__ u, const float* __restrict__ v,
        const u16* __restrict__ W2T, const float* __restrict__ W1,
        const float* __restrict__ b2, const float* __restrict__ pos,
        const float* __restrict__ lframes, const int* __restrict__ batch,
        const int* __restrict__ nbr, const int* __restrict__ cnt,
        float* __restrict__ out0, float* __restrict__ out_pos,
        float* __restrict__ out_batch, float* __restrict__ out_lf) {
    __shared__ u16 h_lds[64 * 264];                       // 64 x 256 bf16, pad 264
    __shared__ f4v relc_lds[64];
    __shared__ int nbr_lds[64];
    __shared__ int s_cnt;

    int blk = blockIdx.x, tid = threadIdx.x;
    int m = ((blk & 7) << 9) | (blk >> 3);                // cloud == XCD (round-robin dispatch)
    int c = m * 4;

    if (tid == 0) s_cnt = cnt[m];
    if (tid < 64) {
        int j = nbr[m * KNB + tid];
        nbr_lds[tid] = j;
        float rx = pos[j * 3 + 0] - pos[c * 3 + 0];
        float ry = pos[j * 3 + 1] - pos[c * 3 + 1];
        float rz = pos[j * 3 + 2] - pos[c * 3 + 2];
        const float* lf = lframes + c * 9;
        f4v r;
        r[0] = lf[0] * rx + lf[1] * ry + lf[2] * rz;
        r[1] = lf[3] * rx + lf[4] * ry + lf[5] * rz;
        r[2] = lf[6] * rx + lf[7] * ry + lf[8] * rz;
        r[3] = 0.0f;
        relc_lds[tid] = r;
    }
    if (tid < 3)  out_pos[m * 3 + tid] = pos[c * 3 + tid];
    if (tid == 3) out_batch[m] = (float)batch[c];
    if (tid >= 4 && tid < 13) out_lf[m * 9 + (tid - 4)] = lframes[c * 9 + (tid - 4)];

    // per-thread column slice (registers, L1-hot global loads)
    int co = (tid & 31) * 8;                              // 8-col slice
    int rs = tid >> 5;                                    // row start (8 rows, stride 8)
    const float* w1c = W1 + 65536;                        // W1 rows 256..258
    f4v vv0 = *(const f4v*)(v + m * 256 + co);
    f4v vv1 = *(const f4v*)(v + m * 256 + co + 4);
    f4v wa0 = *(const f4v*)(w1c + co),        wa1 = *(const f4v*)(w1c + co + 4);
    f4v wb0 = *(const f4v*)(w1c + 256 + co),  wb1 = *(const f4v*)(w1c + 256 + co + 4);
    f4v wc0 = *(const f4v*)(w1c + 512 + co),  wc1 = *(const f4v*)(w1c + 512 + co + 4);
    __syncthreads();

    // phase 1: h = relu(u[nbr] + v + relc @ W1c) -> bf16 LDS (perm-trunc pack)
    #pragma unroll
    for (int ii = 0; ii < 8; ++ii) {
        int k = rs + ii * 8;
        int j = nbr_lds[k];
        f4v r = relc_lds[k];                              // broadcast read
        u4v uu = *(const u4v*)(u + j * 256 + co);         // 16B, lanes 0..31 contiguous 512B
        float p[8];
        #pragma unroll
        for (int e = 0; e < 8; ++e) {
            u16 ue = (u16)((uu[e >> 1] >> ((e & 1) * 16)) & 0xFFFFu);
            float va = (e < 4) ? vv0[e] : vv1[e - 4];
            float a0 = (e < 4) ? wa0[e] : wa1[e - 4];
            float b0 = (e < 4) ? wb0[e] : wb1[e - 4];
            float c0 = (e < 4) ? wc0[e] : wc1[e - 4];
            float pre = fmaf(r[0], a0, fmaf(r[1], b0, fmaf(r[2], c0, va + bf2f(ue))));
            p[e] = fmaxf(pre, 0.0f);
        }
        u4v pk;
        #pragma unroll
        for (int d = 0; d < 4; ++d)
            pk[d] = __builtin_amdgcn_perm(__float_as_uint(p[2 * d + 1]),
                                          __float_as_uint(p[2 * d]), 0x07060302u);
        *(u4v*)&h_lds[k * 264 + co] = pk;
    }
    __syncthreads();

    // phase 2: [64x256] @ [256x256]; wave w -> cols [64w, 64w+64)
    int lane = tid & 63, w = tid >> 6;
    int quad = lane >> 4, l16 = lane & 15;
    int cb = w * 64;
    f4v acc[4][4] = {};
    for (int k0 = 0; k0 < 256; k0 += 32) {
        s8v a[4], b[4];
        for (int rt = 0; rt < 4; ++rt)
            a[rt] = *(const s8v*)&h_lds[(rt * 16 + l16) * 264 + k0 + quad * 8];
        for (int ct = 0; ct < 4; ++ct)
            b[ct] = *(const s8v*)(W2T + (cb + ct * 16 + l16) * 256 + k0 + quad * 8);
        for (int rt = 0; rt < 4; ++rt)
            for (int ct = 0; ct < 4; ++ct)
                acc[rt][ct] = __builtin_amdgcn_mfma_f32_16x16x32_bf16(a[rt], b[ct], acc[rt][ct], 0, 0, 0);
    }
    int cv = s_cnt;
    for (int ct = 0; ct < 4; ++ct) {
        float mx = -__builtin_inff();
        for (int rt = 0; rt < 4; ++rt)
            for (int g = 0; g < 4; ++g) {
                int row = rt * 16 + quad * 4 + g;
                float val = acc[rt][ct][g];
                if (row < cv) mx = fmaxf(mx, val);
            }
        mx = fmaxf(mx, __shfl_xor(mx, 16, 64));
        mx = fmaxf(mx, __shfl_xor(mx, 32, 64));
        if (lane < 16) {
            int col = cb + ct * 16 + l16;
            out0[m * 256 + col] = mx + b2[col];
        }
    }
}

extern "C" void kernel_launch(void* const* d_in, const int* in_sizes, int n_in,
                              void* d_out, int out_size, void* d_ws, size_t ws_size,
                              hipStream_t stream) {
    const float* x       = (const float*)d_in[0];
    const float* pos     = (const float*)d_in[1];
    const int*   batch   = (const int*)d_in[2];
    const float* lframes = (const float*)d_in[3];
    const float* W1      = (const float*)d_in[4];
    const float* b1      = (const float*)d_in[5];
    const float* W2      = (const float*)d_in[6];
    const float* b2      = (const float*)d_in[7];

    float* out       = (float*)d_out;
    float* out_pos   = out + M_CTR * 256;
    float* out_batch = out_pos + M_CTR * 3;
    float* out_lf    = out_batch + M_CTR;

    char* ws = (char*)d_ws;
    u16*   u_ws = (u16*)(ws);                    // N*256 bf16   = 8 MB
    float* v_ws = (float*)(ws + 8388608);        // M*256 f32    = 4 MB
    u16*   W1aT = (u16*)(ws + 12582912);
    u16*   W1bT = (u16*)(ws + 12648448);
    u16*   W2T  = (u16*)(ws + 12713984);
    int*   nbr  = (int*)(ws + 12845056);
    int*   cntp = (int*)(ws + 13893632);

    hipLaunchKernelGGL(ballq_kernel, dim3(M_CTR), dim3(256), 0, stream,
                       pos, nbr, cntp, W1, W2, W1aT, W1bT, W2T);
    hipLaunchKernelGGL(gemm_xw_kernel, dim3(320), dim3(256), 0, stream,
                       x, W1aT, W1bT, b1, u_ws, v_ws);
    hipLaunchKernelGGL(edge_kernel, dim3(M_CTR), dim3(256), 0, stream,
                       u_ws, v_ws, W2T, W1, b2, pos, lframes, batch, nbr, cntp,
                       out, out_pos, out_batch, out_lf);
}